// Round 6
// baseline (398.644 us; speedup 1.0000x reference)
//
#include <hip/hip_runtime.h>

// Problem: nearest = memory[argmax_m cosine(x_row, memory_m)], plus copy of x.
//   x: 65536 x 1024 f32, memory: 40 x 1024 f32, out = [nearest | x-copy]
//
// R6 structure: lane = K-index. Each wave holds 5 memory rows IN REGISTERS
// (pre-scaled by inv32); x streams through registers one row at a time with
// coalesced dwordx4 loads; dot via 80 FMAs + 6-step __shfl_xor butterfly.
// NO LDS, NO barriers, NO m-loads in the hot loop (R1-R5 evidence: those
// per-chunk costs were the 2.6x-over-memory-floor bottleneck).
//
// d_ws layout (bytes):
//   [0,   320) : double inv64[40]
//   [320, 480) : float  inv32[40]
//   [512, 8704): unsigned long long flagbits[1024] (one bit/x-row, 64/word)

#define DIM 1024
#define NMEM 40

constexpr float TAU = 2.5e-4f;   // normalized top-2 gap below which f64 re-resolve

// ---------------- Kernel 1: memory-row inverse norms (f32 + f64) ----------------
__global__ __launch_bounds__(64) void k_norms(const float* __restrict__ mem,
                                              double* __restrict__ inv64,
                                              float* __restrict__ inv32) {
  const int m = blockIdx.x;      // 40 blocks, 1 wave each
  const int lane = threadIdx.x;
  const float* __restrict__ row = mem + (size_t)m * DIM;
  double s = 0.0;
#pragma unroll
  for (int i = 0; i < DIM / 64; ++i) {
    double v = (double)row[lane + 64 * i];
    s = fma(v, v, s);
  }
#pragma unroll
  for (int off = 32; off > 0; off >>= 1) s += __shfl_xor(s, off, 64);
  if (lane == 0) {
    double n = sqrt(s);
    n = (n > 1e-8) ? n : 1e-8;
    inv64[m] = 1.0 / n;
    inv32[m] = (float)(1.0 / n);
  }
}

// ---------------- Kernel 2: fused sims + argmax + gather + x-copy ----------------
// Block = 8 waves (512 thr), 128 x-rows. Wave w owns memory rows [5w,5w+5) in
// registers: mf[j][i] = mem[5w+j][i*256 + lane*4 .. +4) * inv32. Row loop:
// prefetch next row's 4 dwordx4, store x-copy quarter (waves 0-3), 5 dots,
// butterfly reduce, per-wave top2 -> LDS. Epilogue merges, flags, gathers.
__global__ __launch_bounds__(512) void k_main(const float* __restrict__ x,
                                              const float* __restrict__ mem,
                                              const float* __restrict__ inv32,
                                              float* __restrict__ out_near,
                                              float* __restrict__ out_x,
                                              unsigned long long* __restrict__ flagbits) {
  __shared__ float mv1[8][128];
  __shared__ float mv2[8][128];
  __shared__ int   mi1[8][128];
  __shared__ float nxs[128];
  __shared__ int   amax[128];

  const int tid  = threadIdx.x;
  const int lane = tid & 63;
  const int w    = __builtin_amdgcn_readfirstlane(tid >> 6);  // uniform wave id 0..7
  const int mbase = w * 5;
  const int rowbase = blockIdx.x * 128;

  const float4* __restrict__ m4 = (const float4*)mem;

  // preload this wave's 5 memory rows into registers, pre-scaled by inv32
  float4 mf[5][4];
#pragma unroll
  for (int j = 0; j < 5; ++j) {
    const float s = inv32[mbase + j];
#pragma unroll
    for (int i = 0; i < 4; ++i) {
      float4 v = m4[(size_t)(mbase + j) * (DIM / 4) + i * 64 + lane];
      mf[j][i] = make_float4(v.x * s, v.y * s, v.z * s, v.w * s);
    }
  }

  const float4* __restrict__ xr  = (const float4*)x + (size_t)rowbase * (DIM / 4);
  float4* __restrict__ oxr       = (float4*)out_x  + (size_t)rowbase * (DIM / 4);

  float4 bufA[4], bufB[4];
#pragma unroll
  for (int i = 0; i < 4; ++i) bufA[i] = xr[i * 64 + lane];   // row 0

  auto body = [&](float4 (&cur)[4], float4 (&nxt)[4], int r, bool pf) {
    if (pf) {                                // next row's loads issued first
#pragma unroll
      for (int i = 0; i < 4; ++i) nxt[i] = xr[(size_t)(r + 1) * (DIM / 4) + i * 64 + lane];
    }
#pragma unroll
    for (int i = 0; i < 4; ++i)              // x-copy: wave i stores quarter i (waves 4-7 skip)
      if (w == i) oxr[(size_t)r * (DIM / 4) + i * 64 + lane] = cur[i];
    float p[5];
#pragma unroll
    for (int j = 0; j < 5; ++j) {
      float d = 0.f;
#pragma unroll
      for (int i = 0; i < 4; ++i) {
        d = fmaf(cur[i].x, mf[j][i].x, d);
        d = fmaf(cur[i].y, mf[j][i].y, d);
        d = fmaf(cur[i].z, mf[j][i].z, d);
        d = fmaf(cur[i].w, mf[j][i].w, d);
      }
      p[j] = d;
    }
    float nx = 0.f;
    if (w == 0) {                            // only wave 0 tracks ||x||^2
#pragma unroll
      for (int i = 0; i < 4; ++i) {
        nx = fmaf(cur[i].x, cur[i].x, nx);
        nx = fmaf(cur[i].y, cur[i].y, nx);
        nx = fmaf(cur[i].z, cur[i].z, nx);
        nx = fmaf(cur[i].w, cur[i].w, nx);
      }
    }
#pragma unroll
    for (int st = 1; st < 64; st <<= 1) {    // butterfly: all lanes end with full sums
#pragma unroll
      for (int j = 0; j < 5; ++j) p[j] += __shfl_xor(p[j], st, 64);
      if (w == 0) nx += __shfl_xor(nx, st, 64);
    }
    // top2 over this wave's 5 m's (values identical across lanes; strict > keeps lowest m)
    float v1 = -3.4e38f, v2 = -3.4e38f;
    int i1 = mbase;
#pragma unroll
    for (int j = 0; j < 5; ++j) {
      if (p[j] > v1) { v2 = v1; v1 = p[j]; i1 = mbase + j; }
      else if (p[j] > v2) v2 = p[j];
    }
    if (lane == 0) {
      mv1[w][r] = v1; mv2[w][r] = v2; mi1[w][r] = i1;
      if (w == 0) nxs[r] = nx;
    }
  };

  for (int r = 0; r < 128; r += 2) {         // no barriers in this loop
    body(bufA, bufB, r, true);
    body(bufB, bufA, r + 1, r + 1 < 127);
  }
  __syncthreads();

  if (w == 0) {
#pragma unroll
    for (int h = 0; h < 2; ++h) {
      const int rr = lane + 64 * h;
      float b1 = mv1[0][rr], b2 = mv2[0][rr];
      int bi = mi1[0][rr];
#pragma unroll
      for (int g = 1; g < 8; ++g) {          // ascending g = ascending m: ties keep lower m
        float a1 = mv1[g][rr], a2 = mv2[g][rr];
        int ai = mi1[g][rr];
        if (a1 > b1) { b2 = fmaxf(b1, a2); b1 = a1; bi = ai; }
        else         { b2 = fmaxf(b2, a1); }
      }
      float gap = (b1 - b2) * rsqrtf(fmaxf(nxs[rr], 1e-30f));  // normalized top-2 gap
      bool flag = !(gap >= TAU);                                // NaN-safe
      unsigned long long mask = __ballot(flag);
      if (lane == 0) flagbits[blockIdx.x * 2 + h] = mask;       // all 1024 words every call
      amax[rr] = bi;
    }
  }
  __syncthreads();

  // gather-copy memory[amax] -> out_near, coalesced (each of 8 waves does 16 rows)
  float4* __restrict__ onr = (float4*)out_near + (size_t)rowbase * (DIM / 4);
#pragma unroll 1
  for (int rr2 = 0; rr2 < 16; ++rr2) {
    int r = w * 16 + rr2;
    int am = amax[r];
    const float4* __restrict__ src = m4 + (size_t)am * (DIM / 4);
    float4* __restrict__ dst = onr + (size_t)r * (DIM / 4);
#pragma unroll
    for (int jj = 0; jj < 4; ++jj) dst[lane + 64 * jj] = src[lane + 64 * jj];
  }
}

// ---------------- Kernel 3: f64 re-resolution of razor-thin rows ----------------
__global__ __launch_bounds__(256) void k_refine(const float* __restrict__ x,
                                                const float* __restrict__ mem,
                                                const double* __restrict__ inv64,
                                                const unsigned long long* __restrict__ flagbits,
                                                float* __restrict__ out_near) {
  unsigned long long mask = flagbits[blockIdx.x];
  if (mask == 0ull) return;                 // uniform; nearly all blocks exit here
  const int tid = threadIdx.x;
  const int lane = tid & 63;
  const int wid = tid >> 6;
  __shared__ double bval[4];
  __shared__ int bidx[4];
  while (mask) {
    int r = __ffsll(mask) - 1;
    mask &= (mask - 1ull);
    int row = blockIdx.x * 64 + r;
    const float* __restrict__ xr = x + (size_t)row * DIM;
    double xd[16];
#pragma unroll
    for (int i = 0; i < 16; ++i) xd[i] = (double)xr[lane + 64 * i];
    double best = -1e300;
    int bi = 0;
    for (int q = 0; q < 10; ++q) {
      int m = wid * 10 + q;
      const float* __restrict__ mr = mem + (size_t)m * DIM;
      double s = 0.0;
#pragma unroll
      for (int i = 0; i < 16; ++i) s = fma(xd[i], (double)mr[lane + 64 * i], s);
#pragma unroll
      for (int off = 32; off > 0; off >>= 1) s += __shfl_xor(s, off, 64);
      double v = s * inv64[m];              // identical (bitwise) across lanes
      if (v > best) { best = v; bi = m; }   // strict > keeps lowest m on ties
    }
    if (lane == 0) { bval[wid] = best; bidx[wid] = bi; }
    __syncthreads();
    double g = bval[0];
    int gi = bidx[0];
#pragma unroll
    for (int gg = 1; gg < 4; ++gg) {
      if (bval[gg] > g) { g = bval[gg]; gi = bidx[gg]; }
    }
    const float4* __restrict__ src = (const float4*)mem + (size_t)gi * (DIM / 4);
    float4* __restrict__ dst = (float4*)out_near + (size_t)row * (DIM / 4);
    dst[tid] = src[tid];                    // 256 x 16B = full row, coalesced
    __syncthreads();                        // LDS reuse guard for next flagged row
  }
}

extern "C" void kernel_launch(void* const* d_in, const int* in_sizes, int n_in,
                              void* d_out, int out_size, void* d_ws, size_t ws_size,
                              hipStream_t stream) {
  const float* x   = (const float*)d_in[0];
  const float* mem = (const float*)d_in[1];
  // d_in[2] = top_k (unused: reference only consumes idx[:,0], i.e. the argmax)

  const int n_rows = in_sizes[0] / DIM;          // 65536
  float* out_near = (float*)d_out;
  float* out_x    = (float*)d_out + (size_t)n_rows * DIM;

  double* inv64 = (double*)d_ws;
  float*  inv32 = (float*)((char*)d_ws + 320);
  unsigned long long* flagbits = (unsigned long long*)((char*)d_ws + 512);

  hipLaunchKernelGGL(k_norms,  dim3(NMEM), dim3(64),  0, stream, mem, inv64, inv32);
  hipLaunchKernelGGL(k_main,   dim3(n_rows / 128), dim3(512), 0, stream,
                     x, mem, inv32, out_near, out_x, flagbits);
  hipLaunchKernelGGL(k_refine, dim3(n_rows / 64),  dim3(256), 0, stream,
                     x, mem, inv64, flagbits, out_near);
}